// Round 1
// baseline (186.090 us; speedup 1.0000x reference)
//
#include <hip/hip_runtime.h>

typedef __attribute__((ext_vector_type(8))) short bf16x8;
typedef __attribute__((ext_vector_type(4))) float f32x4;
typedef unsigned short u16;
typedef unsigned int u32;

#define S_LEN 2048
#define HD 64
#define NH 16

__device__ __forceinline__ u16 f2bf(float x) {
  u32 u = __builtin_bit_cast(u32, x);
  u += 0x7fffu + ((u >> 16) & 1u);
  return (u16)(u >> 16);
}

// ushort-index swizzle for tiles with 64-ushort (128B) rows:
// byte ^= ((row&7)<<4)  ->  idx ^= ((row&7)<<3)
__device__ __forceinline__ int swz(int idx) {
  return idx ^ (((idx >> 6) & 7) << 3);
}

__global__ void cvt_scale(const float* __restrict__ in, u16* __restrict__ out,
                          int n4, float scale) {
  int i = blockIdx.x * 256 + threadIdx.x;
  if (i < n4) {
    float4 v = reinterpret_cast<const float4*>(in)[i];
    ushort4 o;
    o.x = f2bf(v.x * scale);
    o.y = f2bf(v.y * scale);
    o.z = f2bf(v.z * scale);
    o.w = f2bf(v.w * scale);
    reinterpret_cast<ushort4*>(out)[i] = o;
  }
}

// VT[b][d][kv] = bf16(V[b][kv][d])
__global__ void cvt_vt(const float* __restrict__ V, u16* __restrict__ VT) {
  int i = blockIdx.x * 256 + threadIdx.x;   // over B*64*2048
  int kv = i & (S_LEN - 1);
  int r = i >> 11;
  int d = r & 63;
  int b = r >> 6;
  VT[i] = f2bf(V[((size_t)(b * S_LEN + kv)) * HD + d]);
}

__launch_bounds__(256, 4)
__global__ void attn_fwd(const u16* __restrict__ Qb, const u16* __restrict__ Kb,
                         const u16* __restrict__ VTb, float* __restrict__ out) {
  __shared__ u16 Kt[64 * 64];
  __shared__ u16 VTt[64 * 64];
  __shared__ u16 Pl[4][16 * 64];

  const int tid = threadIdx.x;
  const int w = tid >> 6;        // wave 0..3
  const int l = tid & 63;
  const int c = l & 15;          // lane-in-group
  const int g = l >> 4;          // lane group 0..3

  const int bh = blockIdx.x >> 5;   // (b,h) pair, 32 q-tiles each
  const int qt = blockIdx.x & 31;
  const int b = bh >> 4;
  const int q0 = qt * 64 + w * 16;  // this wave's q rows

  // ---- Q fragments (A-operand): lane holds Q[q0+c][32*kk + 8*g + j] ----
  bf16x8 qf[2];
  {
    const u16* qrow = Qb + ((size_t)(bh * S_LEN + q0 + c)) * HD + 8 * g;
    qf[0] = *reinterpret_cast<const bf16x8*>(qrow);
    qf[1] = *reinterpret_cast<const bf16x8*>(qrow + 32);
  }

  f32x4 oa[4];
  #pragma unroll
  for (int cb = 0; cb < 4; ++cb) oa[cb] = (f32x4){0.f, 0.f, 0.f, 0.f};
  float m_r[4] = {-1e30f, -1e30f, -1e30f, -1e30f};
  float l_r[4] = {0.f, 0.f, 0.f, 0.f};

  const int srow = tid >> 3;   // 0..31 staging row
  const int sch = tid & 7;     // 16B chunk within 128B row

  for (int kv0 = 0; kv0 < S_LEN; kv0 += 64) {
    // ---- stage K tile (row-major [kv][d]) and VT tile (row-major [d][kv]) ----
    #pragma unroll
    for (int hlf = 0; hlf < 2; ++hlf) {
      int r = srow + 32 * hlf;
      int4 kd = *reinterpret_cast<const int4*>(
          Kb + ((size_t)(b * S_LEN + kv0 + r)) * HD + 8 * sch);
      *reinterpret_cast<int4*>(&Kt[swz(r * 64 + 8 * sch)]) = kd;
      int4 vd = *reinterpret_cast<const int4*>(
          VTb + ((size_t)(b * HD + r)) * S_LEN + kv0 + 8 * sch);
      *reinterpret_cast<int4*>(&VTt[swz(r * 64 + 8 * sch)]) = vd;
    }
    __syncthreads();

    // ---- S = Q K^T  (per wave: 16 q-rows x 64 kv-cols) ----
    f32x4 sa[4];
    #pragma unroll
    for (int cb = 0; cb < 4; ++cb) {
      bf16x8 k0 = *reinterpret_cast<const bf16x8*>(&Kt[swz((16 * cb + c) * 64 + 8 * g)]);
      bf16x8 k1 = *reinterpret_cast<const bf16x8*>(&Kt[swz((16 * cb + c) * 64 + 32 + 8 * g)]);
      f32x4 z = (f32x4){0.f, 0.f, 0.f, 0.f};
      z = __builtin_amdgcn_mfma_f32_16x16x32_bf16(qf[0], k0, z, 0, 0, 0);
      sa[cb] = __builtin_amdgcn_mfma_f32_16x16x32_bf16(qf[1], k1, z, 0, 0, 0);
    }

    // ---- online softmax (row r of this wave = q0 + 4*g + r) ----
    float mt[4];
    #pragma unroll
    for (int r = 0; r < 4; ++r)
      mt[r] = fmaxf(fmaxf(sa[0][r], sa[1][r]), fmaxf(sa[2][r], sa[3][r]));
    #pragma unroll
    for (int off = 8; off >= 1; off >>= 1) {
      #pragma unroll
      for (int r = 0; r < 4; ++r)
        mt[r] = fmaxf(mt[r], __shfl_xor(mt[r], off));
    }
    float rs[4];
    #pragma unroll
    for (int r = 0; r < 4; ++r) {
      float mn = fmaxf(m_r[r], mt[r]);
      float corr = __expf(m_r[r] - mn);
      m_r[r] = mn;
      l_r[r] *= corr;
      oa[0][r] *= corr; oa[1][r] *= corr; oa[2][r] *= corr; oa[3][r] *= corr;
      rs[r] = 0.f;
    }
    #pragma unroll
    for (int cb = 0; cb < 4; ++cb) {
      #pragma unroll
      for (int r = 0; r < 4; ++r) {
        float p = __expf(sa[cb][r] - m_r[r]);
        rs[r] += p;
        Pl[w][swz((4 * g + r) * 64 + 16 * cb + c)] = f2bf(p);
      }
    }
    #pragma unroll
    for (int off = 8; off >= 1; off >>= 1) {
      #pragma unroll
      for (int r = 0; r < 4; ++r)
        rs[r] += __shfl_xor(rs[r], off);
    }
    #pragma unroll
    for (int r = 0; r < 4; ++r) l_r[r] += rs[r];

    // ---- O += P V  (A = P from per-wave LDS, B = V via VT tile) ----
    bf16x8 pf0 = *reinterpret_cast<const bf16x8*>(&Pl[w][swz(c * 64 + 8 * g)]);
    bf16x8 pf1 = *reinterpret_cast<const bf16x8*>(&Pl[w][swz(c * 64 + 32 + 8 * g)]);
    #pragma unroll
    for (int cb = 0; cb < 4; ++cb) {
      bf16x8 v0 = *reinterpret_cast<const bf16x8*>(&VTt[swz((16 * cb + c) * 64 + 8 * g)]);
      bf16x8 v1 = *reinterpret_cast<const bf16x8*>(&VTt[swz((16 * cb + c) * 64 + 32 + 8 * g)]);
      oa[cb] = __builtin_amdgcn_mfma_f32_16x16x32_bf16(pf0, v0, oa[cb], 0, 0, 0);
      oa[cb] = __builtin_amdgcn_mfma_f32_16x16x32_bf16(pf1, v1, oa[cb], 0, 0, 0);
    }
    __syncthreads();
  }

  // ---- epilogue: normalize and store fp32 ----
  #pragma unroll
  for (int r = 0; r < 4; ++r) {
    float inv = 1.0f / l_r[r];
    #pragma unroll
    for (int cb = 0; cb < 4; ++cb)
      out[((size_t)(bh * S_LEN + q0 + 4 * g + r)) * HD + 16 * cb + c] = oa[cb][r] * inv;
  }
}

extern "C" void kernel_launch(void* const* d_in, const int* in_sizes, int n_in,
                              void* d_out, int out_size, void* d_ws, size_t ws_size,
                              hipStream_t stream) {
  const float* Q = (const float*)d_in[0];
  const float* K = (const float*)d_in[1];
  const float* V = (const float*)d_in[2];
  float* out = (float*)d_out;

  const int QN = 2 * NH * S_LEN * HD;   // 4,194,304
  const int KN = 2 * S_LEN * HD;        // 262,144
  u16* Qb  = (u16*)d_ws;
  u16* Kb  = Qb + QN;
  u16* VTb = Kb + KN;

  // Q * (1/sqrt(64)) -> bf16   (0.125 is a power of two: exact)
  hipLaunchKernelGGL(cvt_scale, dim3(QN / 4 / 256), dim3(256), 0, stream,
                     Q, Qb, QN / 4, 0.125f);
  // K -> bf16
  hipLaunchKernelGGL(cvt_scale, dim3(KN / 4 / 256), dim3(256), 0, stream,
                     K, Kb, KN / 4, 1.0f);
  // V -> bf16 transposed VT[b][d][kv]
  hipLaunchKernelGGL(cvt_vt, dim3(KN / 256), dim3(256), 0, stream, V, VTb);

  // main flash-attention kernel: 32 (b,h) pairs * 32 q-tiles
  hipLaunchKernelGGL(attn_fwd, dim3(1024), dim3(256), 0, stream, Qb, Kb, VTb, out);
}